// Round 5
// baseline (203.956 us; speedup 1.0000x reference)
//
#include <hip/hip_runtime.h>

// BlockSparseFlashAttention — Phi-3-small blocksparse prefill, MI355X (gfx950)
// S=2048, H=32, HKV=8 (GQA x4), D=128, BLK=64, LOCAL=16, VERT=8, HEAD_SLIDE=1
//
// R5 (R2 96us staged; R3 154us direct/L2-thrash; R4 115us DMA+parity —
// all latency-bound: MfmaUtil <10%, every pipe idle, barrier-serialized):
//  - BARRIER-FREE per-wave pipeline: each wave owns 32 q-rows of one (qb,h),
//    iterates its active key blocks with K/V fragments loaded DIRECT from
//    global bf16 (pre-passed K, V^T), software-prefetched:
//      V frags issued before QK, next-tile K frags issued in two halves
//      around the PV phases -> compiler emits partial vmcnt waits, loads
//      stay in flight across phases (AITER-style), no syncthreads at all.
//  - XCD-PINNED KV: kvh = blk & 7 -> each XCD re-reads only its own 1 MB
//    K/V slice (fits 4 MB per-XCD L2); fixes R3's 195 MB HBM thrash.
//  - 128-thr WGs = 2 independent rh-waves (same kb list -> L1 co-location),
//    grid 1024 (qb descending = LPT), P round-trip via wave-private LDS.
//  - No-max softmax in exp2 domain (validated R4: absmax 0.0156).

typedef __bf16 bf16_t;
typedef __bf16 bf16x4 __attribute__((ext_vector_type(4)));
typedef __bf16 bf16x8 __attribute__((ext_vector_type(8)));
typedef float  fx4    __attribute__((ext_vector_type(4)));

#define SL2E_F 0.1275240614354876f   // (1/sqrt(128)) * log2(e)

// ---------------- pre-pass 1: K fp32 -> bf16 (same [2048][1024] layout) ----
__global__ void cvt_k_kernel(const float* __restrict__ K, bf16_t* __restrict__ Kb)
{
    const size_t i = ((size_t)blockIdx.x * 256 + threadIdx.x) * 8;
    fx4 a = *(const fx4*)(K + i);
    fx4 b = *(const fx4*)(K + i + 4);
    bf16x8 f;
    f[0] = (bf16_t)a[0]; f[1] = (bf16_t)a[1]; f[2] = (bf16_t)a[2]; f[3] = (bf16_t)a[3];
    f[4] = (bf16_t)b[0]; f[5] = (bf16_t)b[1]; f[6] = (bf16_t)b[2]; f[7] = (bf16_t)b[3];
    *(bf16x8*)(Kb + i) = f;
}

// ------------- pre-pass 2: V [2048][1024] fp32 -> V^T [1024][2048] bf16 ----
__global__ void transpose_v_kernel(const float* __restrict__ V, bf16_t* __restrict__ VT)
{
    __shared__ __align__(16) bf16_t T[64 * 72];
    const int s0 = blockIdx.x * 64;
    const int c0 = blockIdx.y * 64;
    const int tx = threadIdx.x & 15, ty = threadIdx.x >> 4;
    fx4 a0 = *(const fx4*)(V + (size_t)(s0 + ty * 4 + 0) * 1024 + c0 + tx * 4);
    fx4 a1 = *(const fx4*)(V + (size_t)(s0 + ty * 4 + 1) * 1024 + c0 + tx * 4);
    fx4 a2 = *(const fx4*)(V + (size_t)(s0 + ty * 4 + 2) * 1024 + c0 + tx * 4);
    fx4 a3 = *(const fx4*)(V + (size_t)(s0 + ty * 4 + 3) * 1024 + c0 + tx * 4);
#pragma unroll
    for (int j = 0; j < 4; ++j) {
        bf16x4 f = { (bf16_t)a0[j], (bf16_t)a1[j], (bf16_t)a2[j], (bf16_t)a3[j] };
        *(bf16x4*)&T[(tx * 4 + j) * 72 + ty * 4] = f;
    }
    __syncthreads();
    const int c = threadIdx.x >> 2, part = threadIdx.x & 3;
    bf16x8 x0 = *(const bf16x8*)&T[c * 72 + part * 16];
    bf16x8 x1 = *(const bf16x8*)&T[c * 72 + part * 16 + 8];
    bf16_t* dst = VT + (size_t)(c0 + c) * 2048 + s0 + part * 16;
    *(bf16x8*)(dst)     = x0;
    *(bf16x8*)(dst + 8) = x1;
}

// ------------------------------- main kernel -------------------------------
__launch_bounds__(128, 2)
__global__ void bsfa_kernel(const float* __restrict__ Q,
                            const bf16_t* __restrict__ Kb,
                            const bf16_t* __restrict__ VT,
                            float* __restrict__ O)
{
    const int blk  = blockIdx.x;
    const int kvh  = blk & 7;                   // XCD-pinned kv head
    const int h    = kvh * 4 + ((blk >> 3) & 3);
    const int qb   = 31 - (blk >> 5);           // LPT: heavy blocks first
    const int rh   = threadIdx.x >> 6;          // independent wave: row half
    const int lane = threadIdx.x & 63;
    const int l15  = lane & 15;
    const int quad = lane >> 4;

    __shared__ __align__(16) bf16_t Pt_all[2][32 * 72];
    bf16_t* Pt = Pt_all[rh];                    // wave-private P region

    const int row0 = qb * 64 + rh * 32;

    const bf16_t* kg = Kb + (size_t)kvh * 128;              // K row stride 1024
    const bf16_t* vg = VT + ((size_t)kvh * 128) * 2048;     // V^T row stride 2048

#define KFRAG(KB, KT, KC) \
    (*(const bf16x8*)(kg + ((size_t)((KB) * 64 + (KT) * 16 + l15)) * 1024 + (KC) * 32 + quad * 8))
#define VFRAG(KB, DT, KCG) \
    (*(const bf16x8*)(vg + ((size_t)((DT) * 16 + l15)) * 2048 + (KB) * 64 + (KCG) * 32 + quad * 8))

    // ---- Q fragments (B operand of S^T = K*Q^T), scale*log2e folded in ----
    bf16x8 qf[2][4];
#pragma unroll
    for (int qt = 0; qt < 2; ++qt) {
        const float* qp = Q + (size_t)(row0 + qt * 16 + l15) * 4096 + h * 128;
#pragma unroll
        for (int kc = 0; kc < 4; ++kc) {
            fx4 a = *(const fx4*)(qp + kc * 32 + quad * 8);
            fx4 b = *(const fx4*)(qp + kc * 32 + quad * 8 + 4);
            bf16x8 f;
            f[0] = (bf16_t)(a[0] * SL2E_F); f[1] = (bf16_t)(a[1] * SL2E_F);
            f[2] = (bf16_t)(a[2] * SL2E_F); f[3] = (bf16_t)(a[3] * SL2E_F);
            f[4] = (bf16_t)(b[0] * SL2E_F); f[5] = (bf16_t)(b[1] * SL2E_F);
            f[6] = (bf16_t)(b[2] * SL2E_F); f[7] = (bf16_t)(b[3] * SL2E_F);
            qf[qt][kc] = f;
        }
    }

    fx4 oacc[8][2];
    const fx4 zero4 = {0.0f, 0.0f, 0.0f, 0.0f};
#pragma unroll
    for (int dt = 0; dt < 8; ++dt)
#pragma unroll
        for (int qt = 0; qt < 2; ++qt)
            oacc[dt][qt] = zero4;

    float l_st[2] = { 0.0f, 0.0f };

    // ---- active-block iteration (wave-uniform scalar control) ----
    int kb = 0;
    while (!((qb - kb < 16) || (((kb + h + 1) & 7) == 0))) ++kb;

    // prime: K fragments for the first tile, in two halves (kc 0-1 / 2-3)
    bf16x8 kfA[8], kfB[8];
#pragma unroll
    for (int c = 0; c < 2; ++c)
#pragma unroll
        for (int t = 0; t < 4; ++t) {
            kfA[c * 4 + t] = KFRAG(kb, t, c);
            kfB[c * 4 + t] = KFRAG(kb, t, 2 + c);
        }

    while (kb >= 0) {
        int nkb = -1;
        for (int t = kb + 1; t <= qb; ++t)
            if ((qb - t < 16) || (((t + h + 1) & 7) == 0)) { nkb = t; break; }

        // ---- issue V frag loads for THIS tile (consumed in PV, after QK) ----
        bf16x8 vf[16];
#pragma unroll
        for (int g = 0; g < 2; ++g)
#pragma unroll
            for (int dt = 0; dt < 8; ++dt)
                vf[g * 8 + dt] = VFRAG(kb, dt, g);

        // ---- S^T = K * Q^T ----
        fx4 sacc[4][2];
#pragma unroll
        for (int kt = 0; kt < 4; ++kt)
#pragma unroll
            for (int qt = 0; qt < 2; ++qt)
                sacc[kt][qt] = zero4;
#pragma unroll
        for (int c = 0; c < 2; ++c)
#pragma unroll
            for (int kt = 0; kt < 4; ++kt)
#pragma unroll
                for (int qt = 0; qt < 2; ++qt)
                    sacc[kt][qt] = __builtin_amdgcn_mfma_f32_16x16x32_bf16(
                        kfA[c * 4 + kt], qf[qt][c], sacc[kt][qt], 0, 0, 0);
#pragma unroll
        for (int c = 0; c < 2; ++c)
#pragma unroll
            for (int kt = 0; kt < 4; ++kt)
#pragma unroll
                for (int qt = 0; qt < 2; ++qt)
                    sacc[kt][qt] = __builtin_amdgcn_mfma_f32_16x16x32_bf16(
                        kfB[c * 4 + kt], qf[qt][2 + c], sacc[kt][qt], 0, 0, 0);

        // ---- causal mask on the diagonal block (log2-domain scores) ----
        if (kb == qb) {
#pragma unroll
            for (int kt = 0; kt < 4; ++kt)
#pragma unroll
                for (int qt = 0; qt < 2; ++qt)
#pragma unroll
                    for (int r = 0; r < 4; ++r) {
                        const int k_in = kt * 16 + quad * 4 + r;
                        const int q_in = rh * 32 + qt * 16 + l15;
                        if (q_in < k_in) sacc[kt][qt][r] = -1e30f;
                    }
        }

        // ---- no-max softmax: p = 2^s; row sums via in-lane + shfl ----
#pragma unroll
        for (int qt = 0; qt < 2; ++qt) {
            float rs = 0.0f;
#pragma unroll
            for (int kt = 0; kt < 4; ++kt)
#pragma unroll
                for (int r = 0; r < 4; ++r) {
                    const float p = exp2f(sacc[kt][qt][r]);
                    sacc[kt][qt][r] = p;
                    rs += p;
                }
            rs += __shfl_xor(rs, 16);
            rs += __shfl_xor(rs, 32);
            l_st[qt] += rs;
        }

        // ---- P -> wave-private LDS, re-read as B-operand frags ----
#pragma unroll
        for (int qt = 0; qt < 2; ++qt)
#pragma unroll
            for (int kt = 0; kt < 4; ++kt) {
                bf16x4 f = { (bf16_t)sacc[kt][qt][0], (bf16_t)sacc[kt][qt][1],
                             (bf16_t)sacc[kt][qt][2], (bf16_t)sacc[kt][qt][3] };
                *(bf16x4*)&Pt[(qt * 16 + l15) * 72 + kt * 16 + quad * 4] = f;
            }
        __asm__ __volatile__("s_waitcnt lgkmcnt(0)" ::: "memory");

        bf16x8 pf[2][2];
#pragma unroll
        for (int qt = 0; qt < 2; ++qt)
#pragma unroll
            for (int kcg = 0; kcg < 2; ++kcg)
                pf[qt][kcg] = *(const bf16x8*)&Pt[(qt * 16 + l15) * 72 + kcg * 32 + quad * 8];

        // ---- prefetch NEXT tile's K (half A), then PV kcg0 ----
        const int pkb = (nkb >= 0) ? nkb : kb;
#pragma unroll
        for (int c = 0; c < 2; ++c)
#pragma unroll
            for (int t = 0; t < 4; ++t)
                kfA[c * 4 + t] = KFRAG(pkb, t, c);

#pragma unroll
        for (int dt = 0; dt < 8; ++dt)
#pragma unroll
            for (int qt = 0; qt < 2; ++qt)
                oacc[dt][qt] = __builtin_amdgcn_mfma_f32_16x16x32_bf16(
                    vf[dt], pf[qt][0], oacc[dt][qt], 0, 0, 0);

        // ---- prefetch NEXT tile's K (half B), then PV kcg1 ----
#pragma unroll
        for (int c = 0; c < 2; ++c)
#pragma unroll
            for (int t = 0; t < 4; ++t)
                kfB[c * 4 + t] = KFRAG(pkb, t, 2 + c);

#pragma unroll
        for (int dt = 0; dt < 8; ++dt)
#pragma unroll
            for (int qt = 0; qt < 2; ++qt)
                oacc[dt][qt] = __builtin_amdgcn_mfma_f32_16x16x32_bf16(
                    vf[8 + dt], pf[qt][1], oacc[dt][qt], 0, 0, 0);

        kb = nkb;
    }

    // ---- epilogue: each wave stores its own 32 rows ----
    const float inv0 = 1.0f / l_st[0];
    const float inv1 = 1.0f / l_st[1];
#pragma unroll
    for (int dt = 0; dt < 8; ++dt)
#pragma unroll
        for (int qt = 0; qt < 2; ++qt) {
            const float inv = qt ? inv1 : inv0;
            fx4 o = oacc[dt][qt] * inv;
            *(fx4*)(O + (size_t)(row0 + qt * 16 + l15) * 4096 + h * 128 + dt * 16 + quad * 4) = o;
        }
}

extern "C" void kernel_launch(void* const* d_in, const int* in_sizes, int n_in,
                              void* d_out, int out_size, void* d_ws, size_t ws_size,
                              hipStream_t stream) {
    (void)in_sizes; (void)n_in; (void)ws_size; (void)out_size;
    const float* q = (const float*)d_in[0];
    const float* k = (const float*)d_in[1];
    const float* v = (const float*)d_in[2];
    float* o = (float*)d_out;

    bf16_t* Kb = (bf16_t*)d_ws;                       // [2048][1024] bf16 = 4 MB
    bf16_t* VT = Kb + (size_t)2048 * 1024;            // [1024][2048] bf16 = 4 MB

    cvt_k_kernel<<<dim3(1024), dim3(256), 0, stream>>>(k, Kb);
    transpose_v_kernel<<<dim3(32, 16), dim3(256), 0, stream>>>(v, VT);
    bsfa_kernel<<<dim3(1024), dim3(128), 0, stream>>>(q, Kb, VT, o);
}

// Round 6
// 141.058 us; speedup vs baseline: 1.4459x; 1.4459x over previous
//
#include <hip/hip_runtime.h>

// BlockSparseFlashAttention — Phi-3-small blocksparse prefill, MI355X (gfx950)
// S=2048, H=32, HKV=8 (GQA x4), D=128, BLK=64, LOCAL=16, VERT=8, HEAD_SLIDE=1
//
// R6. Unified theory of R1-R5: every round was serialized by ONE memory-path
// mistake (R2 scalar staging loads; R3/R4 un-pinned KV -> HBM thrash at 2.2
// TB/s; R5 register-starved direct-global frags -> per-load vmcnt drains).
// R6 combines the three fixes that were never simultaneous:
//  - DMA tile staging (global_load_lds w=16): fire-and-forget, one parallel
//    drain per tile, no VGPR round-trip.       [from R4 — verified correct]
//  - XCD-pinned kvh = blk&7: KV slice (1 MB) resident in its XCD's 4 MB L2.
//                                              [from R5 — FETCH 131->20 MB]
//  - 128-thr WG = 2 rh-waves, BOTH compute every staged tile (qt=2 frag
//    amortization, no parity waste, no inter-wave merge).    [from R2]
//  - softmax denominator via MFMA with a ones-fragment (l rides the PV
//    accumulator) -> deletes the serial 36-add+4-shfl reduce per iter.
//  - no-max exp2-domain softmax (validated R4/R5, absmax 0.0156).
//  - fused single pre-pass kernel (K->bf16 + V->V^T bf16).

typedef __bf16 bf16_t;
typedef __bf16 bf16x4 __attribute__((ext_vector_type(4)));
typedef __bf16 bf16x8 __attribute__((ext_vector_type(8)));
typedef float  fx4    __attribute__((ext_vector_type(4)));

#define SL2E_F 0.1275240614354876f   // (1/sqrt(128)) * log2(e)

__device__ inline void load_lds16(const bf16_t* g, bf16_t* l) {
    __builtin_amdgcn_global_load_lds(
        (const __attribute__((address_space(1))) void*)g,
        (__attribute__((address_space(3))) void*)l, 16, 0, 0);
}

// ---- fused pre-pass: K fp32->bf16 (same layout) + V -> V^T bf16 ----------
// grid 512 x 256thr. Each WG: 4096 K elts converted + one 64x64 V tile
// transposed into VT [1024][2048].
__global__ void prep_kernel(const float* __restrict__ K, const float* __restrict__ V,
                            bf16_t* __restrict__ Kb, bf16_t* __restrict__ VT)
{
    const int blk = blockIdx.x;
    // --- K convert: 16 elts/thread ---
    {
        const size_t base = (size_t)blk * 4096 + (size_t)threadIdx.x * 16;
        fx4 a0 = *(const fx4*)(K + base);
        fx4 a1 = *(const fx4*)(K + base + 4);
        fx4 a2 = *(const fx4*)(K + base + 8);
        fx4 a3 = *(const fx4*)(K + base + 12);
        bf16x8 f0, f1;
        f0[0]=(bf16_t)a0[0]; f0[1]=(bf16_t)a0[1]; f0[2]=(bf16_t)a0[2]; f0[3]=(bf16_t)a0[3];
        f0[4]=(bf16_t)a1[0]; f0[5]=(bf16_t)a1[1]; f0[6]=(bf16_t)a1[2]; f0[7]=(bf16_t)a1[3];
        f1[0]=(bf16_t)a2[0]; f1[1]=(bf16_t)a2[1]; f1[2]=(bf16_t)a2[2]; f1[3]=(bf16_t)a2[3];
        f1[4]=(bf16_t)a3[0]; f1[5]=(bf16_t)a3[1]; f1[6]=(bf16_t)a3[2]; f1[7]=(bf16_t)a3[3];
        *(bf16x8*)(Kb + base)     = f0;
        *(bf16x8*)(Kb + base + 8) = f1;
    }
    // --- V transpose 64x64 tile (s0: seq, c0: channel) ---
    __shared__ __align__(16) bf16_t T[64 * 72];
    const int s0 = (blk & 31) * 64;
    const int c0 = (blk >> 5) * 64;
    const int tx = threadIdx.x & 15, ty = threadIdx.x >> 4;
    fx4 a0 = *(const fx4*)(V + (size_t)(s0 + ty * 4 + 0) * 1024 + c0 + tx * 4);
    fx4 a1 = *(const fx4*)(V + (size_t)(s0 + ty * 4 + 1) * 1024 + c0 + tx * 4);
    fx4 a2 = *(const fx4*)(V + (size_t)(s0 + ty * 4 + 2) * 1024 + c0 + tx * 4);
    fx4 a3 = *(const fx4*)(V + (size_t)(s0 + ty * 4 + 3) * 1024 + c0 + tx * 4);
#pragma unroll
    for (int j = 0; j < 4; ++j) {
        bf16x4 f = { (bf16_t)a0[j], (bf16_t)a1[j], (bf16_t)a2[j], (bf16_t)a3[j] };
        *(bf16x4*)&T[(tx * 4 + j) * 72 + ty * 4] = f;
    }
    __syncthreads();
    const int c = threadIdx.x >> 2, part = threadIdx.x & 3;
    bf16x8 x0 = *(const bf16x8*)&T[c * 72 + part * 16];
    bf16x8 x1 = *(const bf16x8*)&T[c * 72 + part * 16 + 8];
    bf16_t* dst = VT + (size_t)(c0 + c) * 2048 + s0 + part * 16;
    *(bf16x8*)(dst)     = x0;
    *(bf16x8*)(dst + 8) = x1;
}

// ------------------------------- main kernel -------------------------------
__launch_bounds__(128, 2)
__global__ void bsfa_kernel(const float* __restrict__ Q,
                            const bf16_t* __restrict__ Kb,
                            const bf16_t* __restrict__ VT,
                            float* __restrict__ O)
{
    const int blk  = blockIdx.x;
    const int kvh  = blk & 7;                   // XCD-pinned kv head
    const int h    = kvh * 4 + ((blk >> 3) & 3);
    const int qb   = 31 - (blk >> 5);           // heavy query blocks first
    const int tid  = threadIdx.x;               // 0..127
    const int rh   = tid >> 6;                  // wave = row half (32 rows)
    const int lane = tid & 63;
    const int l15  = lane & 15;
    const int quad = lane >> 4;

    __shared__ __align__(16) bf16_t Ks[64 * 128];   // swizzled K tile; P overlay
    __shared__ __align__(16) bf16_t Vs[128 * 64];   // swizzled V^T tile

    bf16_t* Pt = &Ks[rh * 2304];      // wave-private P [32][72] (4608 elts tot)

    const int row0 = qb * 64 + rh * 32;

    const bf16_t* kg = Kb + (size_t)kvh * 128;              // K row stride 1024
    const bf16_t* vg = VT + ((size_t)kvh * 128) * 2048;     // V^T row stride 2048

    // ---- Q fragments (B operand of S^T = K*Q^T), scale*log2e folded in ----
    bf16x8 qf[2][4];
#pragma unroll
    for (int qt = 0; qt < 2; ++qt) {
        const float* qp = Q + (size_t)(row0 + qt * 16 + l15) * 4096 + h * 128;
#pragma unroll
        for (int kc = 0; kc < 4; ++kc) {
            fx4 a = *(const fx4*)(qp + kc * 32 + quad * 8);
            fx4 b = *(const fx4*)(qp + kc * 32 + quad * 8 + 4);
            bf16x8 f;
            f[0] = (bf16_t)(a[0] * SL2E_F); f[1] = (bf16_t)(a[1] * SL2E_F);
            f[2] = (bf16_t)(a[2] * SL2E_F); f[3] = (bf16_t)(a[3] * SL2E_F);
            f[4] = (bf16_t)(b[0] * SL2E_F); f[5] = (bf16_t)(b[1] * SL2E_F);
            f[6] = (bf16_t)(b[2] * SL2E_F); f[7] = (bf16_t)(b[3] * SL2E_F);
            qf[qt][kc] = f;
        }
    }

    // ones fragment: A-operand for the l-via-MFMA trick
    bf16x8 ones;
#pragma unroll
    for (int i = 0; i < 8; ++i) ones[i] = (bf16_t)1.0f;

    fx4 oacc[8][2];
    fx4 lacc[2];
    const fx4 zero4 = {0.0f, 0.0f, 0.0f, 0.0f};
#pragma unroll
    for (int dt = 0; dt < 8; ++dt)
#pragma unroll
        for (int qt = 0; qt < 2; ++qt)
            oacc[dt][qt] = zero4;
    lacc[0] = zero4; lacc[1] = zero4;

    for (int kb = 0; kb <= qb; ++kb) {
        if (!((qb - kb < 16) || (((kb + h + 1) & 7) == 0))) continue;

        // ---- DMA-stage K [64][128] and V^T [128][64] (both waves) ----
        {
            const bf16_t* kt_g = kg + ((size_t)kb << 16);   // kb*64*1024
            const bf16_t* vt_g = vg + ((size_t)kb << 6);    // kb*64
#pragma unroll
            for (int i = 0; i < 8; ++i) {
                const int chunk = i * 128 + tid;            // 16B chunk index
                const int krow = chunk >> 4;
                const int kc   = (chunk & 15) ^ (krow & 15);   // XOR swizzle
                load_lds16(kt_g + (size_t)krow * 1024 + kc * 8, Ks + (size_t)chunk * 8);
                const int vrow = chunk >> 3;
                const int vc   = (chunk & 7) ^ (vrow & 7);
                load_lds16(vt_g + (size_t)vrow * 2048 + vc * 8, Vs + (size_t)chunk * 8);
            }
        }
        __syncthreads();   // barrier 1: DMA drained, tiles resident

        // ---- S^T = K * Q^T (K frags from swizzled LDS) ----
        fx4 sacc[4][2];
#pragma unroll
        for (int kt = 0; kt < 4; ++kt)
#pragma unroll
            for (int qt = 0; qt < 2; ++qt)
                sacc[kt][qt] = zero4;
#pragma unroll
        for (int kc = 0; kc < 4; ++kc)
#pragma unroll
            for (int kt = 0; kt < 4; ++kt) {
                bf16x8 kf = *(const bf16x8*)&Ks[(kt * 16 + l15) * 128 + (((kc * 4 + quad) ^ l15)) * 8];
#pragma unroll
                for (int qt = 0; qt < 2; ++qt)
                    sacc[kt][qt] = __builtin_amdgcn_mfma_f32_16x16x32_bf16(
                        kf, qf[qt][kc], sacc[kt][qt], 0, 0, 0);
            }

        // ---- causal mask on the diagonal block (log2-domain scores) ----
        if (kb == qb) {
#pragma unroll
            for (int kt = 0; kt < 4; ++kt)
#pragma unroll
                for (int qt = 0; qt < 2; ++qt)
#pragma unroll
                    for (int r = 0; r < 4; ++r) {
                        const int k_in = kt * 16 + quad * 4 + r;
                        const int q_in = rh * 32 + qt * 16 + l15;
                        if (q_in < k_in) sacc[kt][qt][r] = -1e30f;
                    }
        }

        // ---- no-max softmax: p = 2^s (no row reduce — l comes from MFMA) ----
#pragma unroll
        for (int kt = 0; kt < 4; ++kt)
#pragma unroll
            for (int qt = 0; qt < 2; ++qt)
#pragma unroll
                for (int r = 0; r < 4; ++r)
                    sacc[kt][qt][r] = exp2f(sacc[kt][qt][r]);

        __syncthreads();   // barrier 2: all K reads done before P overlays Ks

        // ---- P -> wave-private LDS overlay, re-read as B-operand frags ----
#pragma unroll
        for (int qt = 0; qt < 2; ++qt)
#pragma unroll
            for (int kt = 0; kt < 4; ++kt) {
                bf16x4 f = { (bf16_t)sacc[kt][qt][0], (bf16_t)sacc[kt][qt][1],
                             (bf16_t)sacc[kt][qt][2], (bf16_t)sacc[kt][qt][3] };
                *(bf16x4*)&Pt[(qt * 16 + l15) * 72 + kt * 16 + quad * 4] = f;
            }
        __asm__ __volatile__("s_waitcnt lgkmcnt(0)" ::: "memory");

        bf16x8 pf[2][2];
#pragma unroll
        for (int qt = 0; qt < 2; ++qt)
#pragma unroll
            for (int kcg = 0; kcg < 2; ++kcg)
                pf[qt][kcg] = *(const bf16x8*)&Pt[(qt * 16 + l15) * 72 + kcg * 32 + quad * 8];

        // ---- O^T += V^T * P^T ; l += ones * P^T (V frags from swizzled LDS) ----
#pragma unroll
        for (int kcg = 0; kcg < 2; ++kcg) {
#pragma unroll
            for (int dt = 0; dt < 8; ++dt) {
                bf16x8 vf = *(const bf16x8*)&Vs[(dt * 16 + l15) * 64 + (((kcg * 4 + quad) ^ (l15 & 7))) * 8];
#pragma unroll
                for (int qt = 0; qt < 2; ++qt)
                    oacc[dt][qt] = __builtin_amdgcn_mfma_f32_16x16x32_bf16(
                        vf, pf[qt][kcg], oacc[dt][qt], 0, 0, 0);
            }
#pragma unroll
            for (int qt = 0; qt < 2; ++qt)
                lacc[qt] = __builtin_amdgcn_mfma_f32_16x16x32_bf16(
                    ones, pf[qt][kcg], lacc[qt], 0, 0, 0);
        }

        __syncthreads();   // barrier 3: Vs/P reads done before next DMA
    }

    // ---- epilogue: each wave stores its own 32 rows ----
    const float inv0 = 1.0f / lacc[0][0];   // all rows of lacc are identical
    const float inv1 = 1.0f / lacc[1][0];
#pragma unroll
    for (int dt = 0; dt < 8; ++dt)
#pragma unroll
        for (int qt = 0; qt < 2; ++qt) {
            const float inv = qt ? inv1 : inv0;
            fx4 o = oacc[dt][qt] * inv;
            *(fx4*)(O + (size_t)(row0 + qt * 16 + l15) * 4096 + h * 128 + dt * 16 + quad * 4) = o;
        }
}

extern "C" void kernel_launch(void* const* d_in, const int* in_sizes, int n_in,
                              void* d_out, int out_size, void* d_ws, size_t ws_size,
                              hipStream_t stream) {
    (void)in_sizes; (void)n_in; (void)ws_size; (void)out_size;
    const float* q = (const float*)d_in[0];
    const float* k = (const float*)d_in[1];
    const float* v = (const float*)d_in[2];
    float* o = (float*)d_out;

    bf16_t* Kb = (bf16_t*)d_ws;                       // [2048][1024] bf16 = 4 MB
    bf16_t* VT = Kb + (size_t)2048 * 1024;            // [1024][2048] bf16 = 4 MB

    prep_kernel<<<dim3(512), dim3(256), 0, stream>>>(k, v, Kb, VT);
    bsfa_kernel<<<dim3(1024), dim3(128), 0, stream>>>(q, Kb, VT, o);
}